// Round 1
// 934.857 us; speedup vs baseline: 1.1058x; 1.1058x over previous
//
#include <hip/hip_runtime.h>
#include <hip/hip_bf16.h>
#include <cstdint>
#include <cstddef>

// Problem constants (B=1)
#define SEQ  2048
#define HID_ 6144
#define NKV  6400   // QKV_OUT
#define NH_  48
#define HD_  128

typedef unsigned short u16;
typedef __bf16 bf16x8 __attribute__((ext_vector_type(8)));
typedef float  f32x4  __attribute__((ext_vector_type(4)));
typedef unsigned short us8 __attribute__((ext_vector_type(8)));

__device__ __forceinline__ void async_ld16(const void* g, void* l) {
  __builtin_amdgcn_global_load_lds(
      (const __attribute__((address_space(1))) unsigned int*)g,
      (__attribute__((address_space(3))) unsigned int*)l, 16, 0, 0);
}

__device__ __forceinline__ u16 f2b(float f) {
  __hip_bfloat16 h = __float2bfloat16(f);
  return *reinterpret_cast<u16*>(&h);
}

// ---------------------------------------------------------------------------
// fp32 -> bf16 convert, 8 elements/thread (32B load, 16B store). n % 8 == 0.
// ---------------------------------------------------------------------------
__global__ void cvt_f32_bf16(const float* __restrict__ in, u16* __restrict__ out,
                             long n8) {
  const long i = (long)blockIdx.x * blockDim.x + threadIdx.x;
  if (i >= n8) return;
  const long o = i * 8;
  const float4 f0 = *(const float4*)(in + o);
  const float4 f1 = *(const float4*)(in + o + 4);
  us8 v;
  v[0] = f2b(f0.x); v[1] = f2b(f0.y); v[2] = f2b(f0.z); v[3] = f2b(f0.w);
  v[4] = f2b(f1.x); v[5] = f2b(f1.y); v[6] = f2b(f1.z); v[7] = f2b(f1.w);
  *(us8*)(out + o) = v;
}

// ---------------------------------------------------------------------------
// GEMM: C[M,N] = A[M,K] @ B[N,K]^T + bias[N]. A,B bf16, fp32 accum,
// fp32 bias, output type OT (u16 bf16 or float).
// m97 structure: 128x128 tile, BK=32, global_load_lds width=16,
// 4 waves in 2x2, each wave 4x4 tiles of 16x16x32 MFMA.
// ---------------------------------------------------------------------------
template <int N, int K, typename OT>
__global__ __launch_bounds__(256, 2)
void gemm_bt_bias(const u16* __restrict__ A, const u16* __restrict__ B,
                  const float* __restrict__ bias, OT* __restrict__ C) {
  __shared__ u16 As[128 * 32];
  __shared__ u16 Bs[128 * 32];
  const int tid  = threadIdx.x;
  const int lane = tid & 63, wave = tid >> 6;
  const int l15  = lane & 15, quad = lane >> 4;
  const int wm = wave >> 1, wn = wave & 1;
  const int m0 = blockIdx.y * 128, n0 = blockIdx.x * 128;

  f32x4 acc[4][4];
#pragma unroll
  for (int i = 0; i < 4; ++i)
#pragma unroll
    for (int j = 0; j < 4; ++j) acc[i][j] = f32x4{0.f, 0.f, 0.f, 0.f};

  // staging: chunk = tid ; row = tid>>2 ; col8 = (tid&3)*8
  const int rowA0 = tid >> 2, col8 = (tid & 3) * 8;
  const u16* gA = A + (size_t)(m0 + rowA0) * K + col8;
  const u16* gB = B + (size_t)(n0 + rowA0) * K + col8;
  u16* lA = As + tid * 8;  // 16B per chunk, lane-contiguous within wave
  u16* lB = Bs + tid * 8;

  for (int k0 = 0; k0 < K; k0 += 32) {
    async_ld16(gA + k0, lA);
    async_ld16(gA + (size_t)64 * K + k0, lA + 256 * 8);
    async_ld16(gB + k0, lB);
    async_ld16(gB + (size_t)64 * K + k0, lB + 256 * 8);
    __syncthreads();  // drains vmcnt(0): staged tiles visible

    const u16* aBase = As + (wm * 64 + l15) * 32 + quad * 8;
    const u16* bBase = Bs + (wn * 64 + l15) * 32 + quad * 8;
    bf16x8 af[4], bfr[4];
#pragma unroll
    for (int i = 0; i < 4; ++i) {
      af[i]  = *(const bf16x8*)(aBase + i * 16 * 32);
      bfr[i] = *(const bf16x8*)(bBase + i * 16 * 32);
    }
#pragma unroll
    for (int i = 0; i < 4; ++i)
#pragma unroll
      for (int j = 0; j < 4; ++j)
        acc[i][j] = __builtin_amdgcn_mfma_f32_16x16x32_bf16(af[i], bfr[j], acc[i][j], 0, 0, 0);
    __syncthreads();  // protect LDS before next stage
  }

  // epilogue: C/D layout col=lane&15, row=(lane>>4)*4+reg  [m89/m91]
#pragma unroll
  for (int j = 0; j < 4; ++j) {
    const int n = n0 + wn * 64 + j * 16 + l15;
    const float bv = bias[n];
#pragma unroll
    for (int i = 0; i < 4; ++i) {
      const int mrow = m0 + wm * 64 + i * 16 + quad * 4;
#pragma unroll
      for (int r = 0; r < 4; ++r) {
        const float v = acc[i][j][r] + bv;
        if constexpr (sizeof(OT) == 2)
          C[(size_t)(mrow + r) * N + n] = (OT)f2b(v);
        else
          C[(size_t)(mrow + r) * N + n] = (OT)v;
      }
    }
  }
}

// ---------------------------------------------------------------------------
// Multi-query causal flash attention (bf16 in/out, fp32 softmax state).
// Block = (head h, 64 q-rows). 4 waves, wave w owns q-strip [q0+16w, +16).
//
// Round-1 restructure (latency/imbalance fix):
//  * Grid transposed to (h fast, qtile slow) and qtile REVERSED: all heavy
//    (long-loop) blocks dispatch first across all 48 heads -> no tail of
//    late heavy blocks, and the 48 heads co-schedule on the same K/V tiles
//    (MQA: single KV head) for L2 reuse.
//  * K staging moved from global_load_lds to register staging, and both K
//    and V for tile t+1 are PREFETCHED into registers during tile t's
//    compute (T14 async-STAGE split). The vmcnt wait for the prefetch lands
//    at the ds_write at the top of the next iteration, not at the barrier,
//    so ~all global latency hides under QK^T+softmax+PV.
//  LDS stays 43 KB -> 3 blocks/CU; 2 reg sets (K,V) ~= +64 VGPR.
// ---------------------------------------------------------------------------
__global__ __launch_bounds__(256, 3)
void mqa_flash(const u16* __restrict__ qkv, u16* __restrict__ attn) {
  __shared__ u16 Ks[4 * 64 * 32];  // 16 KB, kc-slab layout [kc][64][32]
  __shared__ u16 Vt[128 * 72];     // 18 KB, [d][kv] pad 64->72
  __shared__ u16 Ps[4 * 16 * 72];  // 9 KB, per-wave P[q][kv] pad 64->72
  const int tid  = threadIdx.x;
  const int lane = tid & 63, wave = tid >> 6;
  const int l15  = lane & 15, quad = lane >> 4;
  const int h  = blockIdx.x;                           // head (fast dim)
  const int qb = (int)gridDim.y - 1 - (int)blockIdx.y; // heavy tiles first
  const int q0 = qb * 64;
  const float scale = 0.088388347648318447f;  // 1/sqrt(128)

  // Q fragments in registers: A-operand A[m=lane&15][k=quad*8+j]
  bf16x8 qf[4];
  {
    const u16* qp = qkv + (size_t)(q0 + wave * 16 + l15) * NKV + h * HD_ + quad * 8;
#pragma unroll
    for (int kc = 0; kc < 4; ++kc) qf[kc] = *(const bf16x8*)(qp + kc * 32);
  }

  f32x4 oacc[8];
#pragma unroll
  for (int nd = 0; nd < 8; ++nd) oacc[nd] = f32x4{0.f, 0.f, 0.f, 0.f};
  float mrun[4], lrun[4];
#pragma unroll
  for (int r = 0; r < 4; ++r) { mrun[r] = -1e30f; lrun[r] = 0.f; }

  // staging index maps
  const int krow = tid >> 2, kc8 = (tid & 3) * 8;  // K: row, 16B col slot
  const int kv2 = lane & 31;                // V: kv pair 0..31
  const int dg  = wave * 2 + (lane >> 5);   // V: d group 0..7 (16 d each)

  // --- register-staged tile load (K: 4x16B, V: 4x16B per thread) ---
  auto load_tile = [&](int t, us8* kr, us8* vr) {
    const int kv0 = t * 64;
    const u16* kp = qkv + (size_t)(kv0 + krow) * NKV + HID_ + kc8;
#pragma unroll
    for (int r = 0; r < 4; ++r) kr[r] = *(const us8*)(kp + r * 32);
    const u16* vp = qkv + (size_t)(kv0 + kv2 * 2) * NKV + HID_ + HD_ + dg * 16;
    vr[0] = *(const us8*)(vp);
    vr[1] = *(const us8*)(vp + 8);
    vr[2] = *(const us8*)(vp + NKV);
    vr[3] = *(const us8*)(vp + NKV + 8);
  };

  // --- registers -> LDS (K linear into kc-slabs, V transposed+packed) ---
  auto stage_tile = [&](const us8* kr, const us8* vr) {
    u16* kd = Ks + tid * 8;
#pragma unroll
    for (int r = 0; r < 4; ++r) *(us8*)(kd + r * 2048) = kr[r];
#pragma unroll
    for (int i = 0; i < 8; ++i) {
      unsigned v0 = (unsigned)vr[0][i] | ((unsigned)vr[2][i] << 16);
      unsigned v1 = (unsigned)vr[1][i] | ((unsigned)vr[3][i] << 16);
      *(unsigned*)(Vt + (dg * 16 + i) * 72 + kv2 * 2) = v0;
      *(unsigned*)(Vt + (dg * 16 + 8 + i) * 72 + kv2 * 2) = v1;
    }
  };

  auto compute_tile = [&](int t) {
    const int kv0 = t * 64;
    // --- S = Q K^T  (16q x 64kv per wave) ---
    f32x4 s[4];
#pragma unroll
    for (int nt = 0; nt < 4; ++nt) {
      f32x4 c4 = f32x4{0.f, 0.f, 0.f, 0.f};
#pragma unroll
      for (int kc = 0; kc < 4; ++kc) {
        bf16x8 kf = *(const bf16x8*)(Ks + kc * 2048 + (nt * 16 + l15) * 32 + quad * 8);
        c4 = __builtin_amdgcn_mfma_f32_16x16x32_bf16(qf[kc], kf, c4, 0, 0, 0);
      }
      s[nt] = c4;
    }

    // --- scale (+ mask only on the diagonal tile) + row max ---
    float mt[4] = {-1e30f, -1e30f, -1e30f, -1e30f};
    if (t == qb) {
#pragma unroll
      for (int nt = 0; nt < 4; ++nt) {
        const int kvg = kv0 + nt * 16 + l15;
#pragma unroll
        for (int r = 0; r < 4; ++r) {
          const int qg = q0 + wave * 16 + quad * 4 + r;
          float v = s[nt][r] * scale;
          v = (kvg <= qg) ? v : -1e30f;
          s[nt][r] = v;
          mt[r] = fmaxf(mt[r], v);
        }
      }
    } else {
#pragma unroll
      for (int nt = 0; nt < 4; ++nt)
#pragma unroll
        for (int r = 0; r < 4; ++r) {
          const float v = s[nt][r] * scale;
          s[nt][r] = v;
          mt[r] = fmaxf(mt[r], v);
        }
    }
#pragma unroll
    for (int off = 1; off < 16; off <<= 1)
#pragma unroll
      for (int r = 0; r < 4; ++r) mt[r] = fmaxf(mt[r], __shfl_xor(mt[r], off));

    float alpha[4], rsum[4];
#pragma unroll
    for (int r = 0; r < 4; ++r) {
      const float mnew = fmaxf(mrun[r], mt[r]);
      alpha[r] = __expf(mrun[r] - mnew);
      mrun[r] = mnew;
      rsum[r] = 0.f;
    }
    // --- P = exp(s - m), write to LDS in [q][kv] layout ---
    u16* pw = Ps + wave * (16 * 72);
#pragma unroll
    for (int nt = 0; nt < 4; ++nt)
#pragma unroll
      for (int r = 0; r < 4; ++r) {
        const float p = __expf(s[nt][r] - mrun[r]);
        rsum[r] += p;
        pw[(quad * 4 + r) * 72 + nt * 16 + l15] = f2b(p);
      }
#pragma unroll
    for (int off = 1; off < 16; off <<= 1)
#pragma unroll
      for (int r = 0; r < 4; ++r) rsum[r] += __shfl_xor(rsum[r], off);
#pragma unroll
    for (int r = 0; r < 4; ++r) lrun[r] = lrun[r] * alpha[r] + rsum[r];
#pragma unroll
    for (int nd = 0; nd < 8; ++nd)
#pragma unroll
      for (int r = 0; r < 4; ++r) oacc[nd][r] *= alpha[r];

    // --- O += P @ V ---
#pragma unroll
    for (int kc2 = 0; kc2 < 2; ++kc2) {
      bf16x8 pf = *(const bf16x8*)(pw + l15 * 72 + kc2 * 32 + quad * 8);
#pragma unroll
      for (int nd = 0; nd < 8; ++nd) {
        bf16x8 vf = *(const bf16x8*)(Vt + (nd * 16 + l15) * 72 + kc2 * 32 + quad * 8);
        oacc[nd] = __builtin_amdgcn_mfma_f32_16x16x32_bf16(pf, vf, oacc[nd], 0, 0, 0);
      }
    }
  };

  // --- pipelined main loop: stage t from regs, prefetch t+1 into regs ---
  us8 kA[4], vA[4], kB[4], vB[4];
  load_tile(0, kA, vA);
  for (int t = 0; t <= qb; ++t) {
    const int tn = (t < qb) ? t + 1 : t;  // last iter: harmless reload
    if (!(t & 1)) {
      stage_tile(kA, vA);   // waits vmcnt for kA/vA here (not at barrier)
      load_tile(tn, kB, vB);
    } else {
      stage_tile(kB, vB);
      load_tile(tn, kA, vA);
    }
    __syncthreads();   // staged K/V visible to all waves
    compute_tile(t);
    __syncthreads();   // all reads done; LDS reusable next iter
  }

  // --- epilogue: O / l -> attn[S, HID] (bf16) ---
#pragma unroll
  for (int r = 0; r < 4; ++r) {
    const int qg = q0 + wave * 16 + quad * 4 + r;
    const float inv = 1.f / lrun[r];
#pragma unroll
    for (int nd = 0; nd < 8; ++nd)
      attn[(size_t)qg * HID_ + h * HD_ + nd * 16 + l15] = f2b(oacc[nd][r] * inv);
  }
}

// ---------------------------------------------------------------------------
extern "C" void kernel_launch(void* const* d_in, const int* in_sizes, int n_in,
                              void* d_out, int out_size, void* d_ws, size_t ws_size,
                              hipStream_t stream) {
  const float* x    = (const float*)d_in[0];  // [2048, 6144] fp32
  const float* wqkv = (const float*)d_in[1];  // [6400, 6144] fp32
  const float* bqkv = (const float*)d_in[2];  // [6400] fp32
  const float* wo   = (const float*)d_in[3];  // [6144, 6144] fp32
  const float* bo   = (const float*)d_in[4];  // [6144] fp32
  float* out = (float*)d_out;                 // [2048, 6144] fp32

  // workspace layout (all 16B-aligned)
  u16* xb     = (u16*)d_ws;                             // 25.2 MB
  u16* wqkvb  = xb + (size_t)SEQ * HID_;                // 78.6 MB
  u16* wob    = wqkvb + (size_t)NKV * HID_;             // 75.5 MB
  u16* qkvws  = wob + (size_t)HID_ * HID_;              // 26.2 MB
  u16* attnws = qkvws + (size_t)SEQ * NKV;              // 25.2 MB
  // total ~230.7 MB

  // 0) fp32 -> bf16 converts
  {
    const long n8x = (long)SEQ * HID_ / 8;
    cvt_f32_bf16<<<(n8x + 255) / 256, 256, 0, stream>>>(x, xb, n8x);
    const long n8q = (long)NKV * HID_ / 8;
    cvt_f32_bf16<<<(n8q + 255) / 256, 256, 0, stream>>>(wqkv, wqkvb, n8q);
    const long n8o = (long)HID_ * HID_ / 8;
    cvt_f32_bf16<<<(n8o + 255) / 256, 256, 0, stream>>>(wo, wob, n8o);
  }

  // 1) fused QKV projection (bf16 out)
  gemm_bt_bias<NKV, HID_, u16><<<dim3(NKV / 128, SEQ / 128), 256, 0, stream>>>(
      xb, wqkvb, bqkv, qkvws);
  // 2) multi-query causal flash attention (h fast, heavy q-tiles first)
  mqa_flash<<<dim3(NH_, SEQ / 64), 256, 0, stream>>>(qkvws, attnws);
  // 3) output projection (fp32 out)
  gemm_bt_bias<HID_, HID_, float><<<dim3(HID_ / 128, SEQ / 128), 256, 0, stream>>>(
      attnws, wob, bo, out);
}

// Round 2
// 921.838 us; speedup vs baseline: 1.1214x; 1.0141x over previous
//
#include <hip/hip_runtime.h>
#include <hip/hip_bf16.h>
#include <cstdint>
#include <cstddef>

// Problem constants (B=1)
#define SEQ  2048
#define HID_ 6144
#define NKV  6400   // QKV_OUT
#define NH_  48
#define HD_  128

typedef unsigned short u16;
typedef __bf16 bf16x8 __attribute__((ext_vector_type(8)));
typedef float  f32x4  __attribute__((ext_vector_type(4)));
typedef unsigned short us8 __attribute__((ext_vector_type(8)));

__device__ __forceinline__ void async_ld16(const void* g, void* l) {
  __builtin_amdgcn_global_load_lds(
      (const __attribute__((address_space(1))) unsigned int*)g,
      (__attribute__((address_space(3))) unsigned int*)l, 16, 0, 0);
}

__device__ __forceinline__ u16 f2b(float f) {
  __hip_bfloat16 h = __float2bfloat16(f);
  return *reinterpret_cast<u16*>(&h);
}

// ---------------------------------------------------------------------------
// fp32 -> bf16 convert, 8 elements/thread (32B load, 16B store). n % 8 == 0.
// ---------------------------------------------------------------------------
__global__ void cvt_f32_bf16(const float* __restrict__ in, u16* __restrict__ out,
                             long n8) {
  const long i = (long)blockIdx.x * blockDim.x + threadIdx.x;
  if (i >= n8) return;
  const long o = i * 8;
  const float4 f0 = *(const float4*)(in + o);
  const float4 f1 = *(const float4*)(in + o + 4);
  us8 v;
  v[0] = f2b(f0.x); v[1] = f2b(f0.y); v[2] = f2b(f0.z); v[3] = f2b(f0.w);
  v[4] = f2b(f1.x); v[5] = f2b(f1.y); v[6] = f2b(f1.z); v[7] = f2b(f1.w);
  *(us8*)(out + o) = v;
}

// ---------------------------------------------------------------------------
// GEMM v2: C[M=2048, N] = A[M,K] @ B[N,K]^T + bias[N].
// 256x256 tile, BK=32, 512 threads (8 waves, 2M x 4N), per-wave 128x64 out.
// Counted-vmcnt deep pipeline (T3+T4): 4-slot LDS ring (128 KB), prefetch
// distance 3 via global_load_lds; raw s_barrier + s_waitcnt vmcnt(12) in
// steady state (NEVER __syncthreads -> no vmcnt(0) drain). Ring safety:
// stage(t+3) overwrites slot (t-1)&3 whose reads finished before iter t-1's
// end barrier; landing of tile t guaranteed by vmcnt(12) (leaves t+1..t+3
// in flight) + barrier. BK=32 (64 B rows) makes frag ds_read_b128
// conflict-free without swizzle (l15 bit0 -> addr bit6, quad -> bits 4-5:
// all 8 bank-slots uniform). T1 bijective XCD swizzle (grid % 8 == 0),
// grouped so 8 consecutive blocks share one B-panel per XCD.
// ---------------------------------------------------------------------------
template <int N, int K, typename OT>
__global__ __launch_bounds__(512, 2)
void gemm256(const u16* __restrict__ A, const u16* __restrict__ B,
             const float* __restrict__ bias, OT* __restrict__ C) {
  __shared__ u16 lds_[4 * 2 * 8192];  // 4 slots x (A 16KB + B 16KB) = 128 KB
  constexpr int NT = K / 32;

  const int tid  = threadIdx.x;
  const int lane = tid & 63, wave = tid >> 6;
  const int l15  = lane & 15, quad = lane >> 4;
  const int wm = wave >> 2, wn = wave & 3;  // 2M x 4N wave grid

  // XCD-aware bijective swizzle (gridDim.x % 8 == 0), B-panel grouped.
  const int nb  = (int)gridDim.x;
  const int cpx = nb >> 3;
  const int swz = ((int)blockIdx.x & 7) * cpx + ((int)blockIdx.x >> 3);
  const int by  = swz & 7;    // M-tile (M=2048 -> 8 tiles)
  const int bx  = swz >> 3;   // N-tile
  const int m0 = by * 256, n0 = bx * 256;

  f32x4 acc[8][4];
#pragma unroll
  for (int i = 0; i < 8; ++i)
#pragma unroll
    for (int j = 0; j < 4; ++j) acc[i][j] = f32x4{0.f, 0.f, 0.f, 0.f};

  // staging: chunk c = sweep*512 + tid ; row = c>>2 ; col8 = (c&3)*8
  const int rowc = tid >> 2, col8 = (tid & 3) * 8;
  const u16* gA0 = A + (size_t)(m0 + rowc) * K + col8;
  const u16* gA1 = gA0 + (size_t)128 * K;
  const u16* gB0 = B + (size_t)(n0 + rowc) * K + col8;
  const u16* gB1 = gB0 + (size_t)128 * K;

  auto stage = [&](int t) {
    u16* s0 = lds_ + (t & 3) * 16384;
    const int k0 = t * 32;
    async_ld16(gA0 + k0, s0 + tid * 8);
    async_ld16(gA1 + k0, s0 + 4096 + tid * 8);
    async_ld16(gB0 + k0, s0 + 8192 + tid * 8);
    async_ld16(gB1 + k0, s0 + 8192 + 4096 + tid * 8);
  };

  // prologue: fill 3 ring slots (12 loads in flight)
  stage(0); stage(1); stage(2);

  for (int t = 0; t < NT; ++t) {
    if (t + 3 < NT) stage(t + 3);
    // wait for tile t's 4 loads: leave min(3, NT-1-t) tiles in flight
    const int rem = NT - 1 - t;
    if (rem >= 3)      asm volatile("s_waitcnt vmcnt(12)" ::: "memory");
    else if (rem == 2) asm volatile("s_waitcnt vmcnt(8)" ::: "memory");
    else if (rem == 1) asm volatile("s_waitcnt vmcnt(4)" ::: "memory");
    else               asm volatile("s_waitcnt vmcnt(0)" ::: "memory");
    __builtin_amdgcn_s_barrier();          // all waves' tile-t chunks landed
    __builtin_amdgcn_sched_barrier(0);

    const u16* sa = lds_ + (t & 3) * 16384 + (wm * 128 + l15) * 32 + quad * 8;
    const u16* sb = lds_ + (t & 3) * 16384 + 8192 + (wn * 64 + l15) * 32 + quad * 8;
    bf16x8 af[8], bfv[4];
#pragma unroll
    for (int i = 0; i < 8; ++i) af[i] = *(const bf16x8*)(sa + i * 512);
#pragma unroll
    for (int j = 0; j < 4; ++j) bfv[j] = *(const bf16x8*)(sb + j * 512);

    __builtin_amdgcn_s_setprio(1);
#pragma unroll
    for (int i = 0; i < 8; ++i)
#pragma unroll
      for (int j = 0; j < 4; ++j)
        acc[i][j] = __builtin_amdgcn_mfma_f32_16x16x32_bf16(af[i], bfv[j], acc[i][j], 0, 0, 0);
    __builtin_amdgcn_s_setprio(0);

    __builtin_amdgcn_sched_barrier(0);
    __builtin_amdgcn_s_barrier();          // slot (t&3) reusable at iter t+1
    __builtin_amdgcn_sched_barrier(0);
  }

  // epilogue: C/D layout col=lane&15, row=(lane>>4)*4+reg  [m89/m91]
#pragma unroll
  for (int j = 0; j < 4; ++j) {
    const int n = n0 + wn * 64 + j * 16 + l15;
    const float bv = bias[n];
#pragma unroll
    for (int i = 0; i < 8; ++i) {
      const int mr = m0 + wm * 128 + i * 16 + quad * 4;
#pragma unroll
      for (int r = 0; r < 4; ++r) {
        const float v = acc[i][j][r] + bv;
        if constexpr (sizeof(OT) == 2)
          C[(size_t)(mr + r) * N + n] = (OT)f2b(v);
        else
          C[(size_t)(mr + r) * N + n] = (OT)v;
      }
    }
  }
}

// ---------------------------------------------------------------------------
// Multi-query causal flash attention (bf16 in/out, fp32 softmax state).
// (unchanged from round 1: heavy-tiles-first grid + reg-staged K/V with
// distance-1 prefetch; dropped out of top-5 dispatches)
// ---------------------------------------------------------------------------
__global__ __launch_bounds__(256, 3)
void mqa_flash(const u16* __restrict__ qkv, u16* __restrict__ attn) {
  __shared__ u16 Ks[4 * 64 * 32];  // 16 KB, kc-slab layout [kc][64][32]
  __shared__ u16 Vt[128 * 72];     // 18 KB, [d][kv] pad 64->72
  __shared__ u16 Ps[4 * 16 * 72];  // 9 KB, per-wave P[q][kv] pad 64->72
  const int tid  = threadIdx.x;
  const int lane = tid & 63, wave = tid >> 6;
  const int l15  = lane & 15, quad = lane >> 4;
  const int h  = blockIdx.x;                           // head (fast dim)
  const int qb = (int)gridDim.y - 1 - (int)blockIdx.y; // heavy tiles first
  const int q0 = qb * 64;
  const float scale = 0.088388347648318447f;  // 1/sqrt(128)

  bf16x8 qf[4];
  {
    const u16* qp = qkv + (size_t)(q0 + wave * 16 + l15) * NKV + h * HD_ + quad * 8;
#pragma unroll
    for (int kc = 0; kc < 4; ++kc) qf[kc] = *(const bf16x8*)(qp + kc * 32);
  }

  f32x4 oacc[8];
#pragma unroll
  for (int nd = 0; nd < 8; ++nd) oacc[nd] = f32x4{0.f, 0.f, 0.f, 0.f};
  float mrun[4], lrun[4];
#pragma unroll
  for (int r = 0; r < 4; ++r) { mrun[r] = -1e30f; lrun[r] = 0.f; }

  const int krow = tid >> 2, kc8 = (tid & 3) * 8;
  const int kv2 = lane & 31;
  const int dg  = wave * 2 + (lane >> 5);

  auto load_tile = [&](int t, us8* kr, us8* vr) {
    const int kv0 = t * 64;
    const u16* kp = qkv + (size_t)(kv0 + krow) * NKV + HID_ + kc8;
#pragma unroll
    for (int r = 0; r < 4; ++r) kr[r] = *(const us8*)(kp + r * 32);
    const u16* vp = qkv + (size_t)(kv0 + kv2 * 2) * NKV + HID_ + HD_ + dg * 16;
    vr[0] = *(const us8*)(vp);
    vr[1] = *(const us8*)(vp + 8);
    vr[2] = *(const us8*)(vp + NKV);
    vr[3] = *(const us8*)(vp + NKV + 8);
  };

  auto stage_tile = [&](const us8* kr, const us8* vr) {
    u16* kd = Ks + tid * 8;
#pragma unroll
    for (int r = 0; r < 4; ++r) *(us8*)(kd + r * 2048) = kr[r];
#pragma unroll
    for (int i = 0; i < 8; ++i) {
      unsigned v0 = (unsigned)vr[0][i] | ((unsigned)vr[2][i] << 16);
      unsigned v1 = (unsigned)vr[1][i] | ((unsigned)vr[3][i] << 16);
      *(unsigned*)(Vt + (dg * 16 + i) * 72 + kv2 * 2) = v0;
      *(unsigned*)(Vt + (dg * 16 + 8 + i) * 72 + kv2 * 2) = v1;
    }
  };

  auto compute_tile = [&](int t) {
    const int kv0 = t * 64;
    f32x4 s[4];
#pragma unroll
    for (int nt = 0; nt < 4; ++nt) {
      f32x4 c4 = f32x4{0.f, 0.f, 0.f, 0.f};
#pragma unroll
      for (int kc = 0; kc < 4; ++kc) {
        bf16x8 kf = *(const bf16x8*)(Ks + kc * 2048 + (nt * 16 + l15) * 32 + quad * 8);
        c4 = __builtin_amdgcn_mfma_f32_16x16x32_bf16(qf[kc], kf, c4, 0, 0, 0);
      }
      s[nt] = c4;
    }

    float mt[4] = {-1e30f, -1e30f, -1e30f, -1e30f};
    if (t == qb) {
#pragma unroll
      for (int nt = 0; nt < 4; ++nt) {
        const int kvg = kv0 + nt * 16 + l15;
#pragma unroll
        for (int r = 0; r < 4; ++r) {
          const int qg = q0 + wave * 16 + quad * 4 + r;
          float v = s[nt][r] * scale;
          v = (kvg <= qg) ? v : -1e30f;
          s[nt][r] = v;
          mt[r] = fmaxf(mt[r], v);
        }
      }
    } else {
#pragma unroll
      for (int nt = 0; nt < 4; ++nt)
#pragma unroll
        for (int r = 0; r < 4; ++r) {
          const float v = s[nt][r] * scale;
          s[nt][r] = v;
          mt[r] = fmaxf(mt[r], v);
        }
    }
#pragma unroll
    for (int off = 1; off < 16; off <<= 1)
#pragma unroll
      for (int r = 0; r < 4; ++r) mt[r] = fmaxf(mt[r], __shfl_xor(mt[r], off));

    float alpha[4], rsum[4];
#pragma unroll
    for (int r = 0; r < 4; ++r) {
      const float mnew = fmaxf(mrun[r], mt[r]);
      alpha[r] = __expf(mrun[r] - mnew);
      mrun[r] = mnew;
      rsum[r] = 0.f;
    }
    u16* pw = Ps + wave * (16 * 72);
#pragma unroll
    for (int nt = 0; nt < 4; ++nt)
#pragma unroll
      for (int r = 0; r < 4; ++r) {
        const float p = __expf(s[nt][r] - mrun[r]);
        rsum[r] += p;
        pw[(quad * 4 + r) * 72 + nt * 16 + l15] = f2b(p);
      }
#pragma unroll
    for (int off = 1; off < 16; off <<= 1)
#pragma unroll
      for (int r = 0; r < 4; ++r) rsum[r] += __shfl_xor(rsum[r], off);
#pragma unroll
    for (int r = 0; r < 4; ++r) lrun[r] = lrun[r] * alpha[r] + rsum[r];
#pragma unroll
    for (int nd = 0; nd < 8; ++nd)
#pragma unroll
      for (int r = 0; r < 4; ++r) oacc[nd][r] *= alpha[r];

#pragma unroll
    for (int kc2 = 0; kc2 < 2; ++kc2) {
      bf16x8 pf = *(const bf16x8*)(pw + l15 * 72 + kc2 * 32 + quad * 8);
#pragma unroll
      for (int nd = 0; nd < 8; ++nd) {
        bf16x8 vf = *(const bf16x8*)(Vt + (nd * 16 + l15) * 72 + kc2 * 32 + quad * 8);
        oacc[nd] = __builtin_amdgcn_mfma_f32_16x16x32_bf16(pf, vf, oacc[nd], 0, 0, 0);
      }
    }
  };

  us8 kA[4], vA[4], kB[4], vB[4];
  load_tile(0, kA, vA);
  for (int t = 0; t <= qb; ++t) {
    const int tn = (t < qb) ? t + 1 : t;
    if (!(t & 1)) {
      stage_tile(kA, vA);
      load_tile(tn, kB, vB);
    } else {
      stage_tile(kB, vB);
      load_tile(tn, kA, vA);
    }
    __syncthreads();
    compute_tile(t);
    __syncthreads();
  }

#pragma unroll
  for (int r = 0; r < 4; ++r) {
    const int qg = q0 + wave * 16 + quad * 4 + r;
    const float inv = 1.f / lrun[r];
#pragma unroll
    for (int nd = 0; nd < 8; ++nd)
      attn[(size_t)qg * HID_ + h * HD_ + nd * 16 + l15] = f2b(oacc[nd][r] * inv);
  }
}

// ---------------------------------------------------------------------------
extern "C" void kernel_launch(void* const* d_in, const int* in_sizes, int n_in,
                              void* d_out, int out_size, void* d_ws, size_t ws_size,
                              hipStream_t stream) {
  const float* x    = (const float*)d_in[0];  // [2048, 6144] fp32
  const float* wqkv = (const float*)d_in[1];  // [6400, 6144] fp32
  const float* bqkv = (const float*)d_in[2];  // [6400] fp32
  const float* wo   = (const float*)d_in[3];  // [6144, 6144] fp32
  const float* bo   = (const float*)d_in[4];  // [6144] fp32
  float* out = (float*)d_out;                 // [2048, 6144] fp32

  // workspace layout (all 16B-aligned)
  u16* xb     = (u16*)d_ws;                             // 25.2 MB
  u16* wqkvb  = xb + (size_t)SEQ * HID_;                // 78.6 MB
  u16* wob    = wqkvb + (size_t)NKV * HID_;             // 75.5 MB
  u16* qkvws  = wob + (size_t)HID_ * HID_;              // 26.2 MB
  u16* attnws = qkvws + (size_t)SEQ * NKV;              // 25.2 MB
  // total ~230.7 MB

  // 0) fp32 -> bf16 converts
  {
    const long n8x = (long)SEQ * HID_ / 8;
    cvt_f32_bf16<<<(n8x + 255) / 256, 256, 0, stream>>>(x, xb, n8x);
    const long n8q = (long)NKV * HID_ / 8;
    cvt_f32_bf16<<<(n8q + 255) / 256, 256, 0, stream>>>(wqkv, wqkvb, n8q);
    const long n8o = (long)HID_ * HID_ / 8;
    cvt_f32_bf16<<<(n8o + 255) / 256, 256, 0, stream>>>(wo, wob, n8o);
  }

  // 1) fused QKV projection (bf16 out): grid 25*8 = 200 blocks (%8==0)
  gemm256<NKV, HID_, u16><<<dim3(200), 512, 0, stream>>>(xb, wqkvb, bqkv, qkvws);
  // 2) multi-query causal flash attention (h fast, heavy q-tiles first)
  mqa_flash<<<dim3(NH_, SEQ / 64), 256, 0, stream>>>(qkvws, attnws);
  // 3) output projection (fp32 out): grid 24*8 = 192 blocks (%8==0)
  gemm256<HID_, HID_, float><<<dim3(192), 512, 0, stream>>>(attnws, wob, bo, out);
}

// Round 3
// 873.465 us; speedup vs baseline: 1.1835x; 1.0554x over previous
//
#include <hip/hip_runtime.h>
#include <hip/hip_bf16.h>
#include <cstdint>
#include <cstddef>

// Problem constants (B=1)
#define SEQ  2048
#define HID_ 6144
#define NKV  6400   // QKV_OUT
#define NH_  48
#define HD_  128

typedef unsigned short u16;
typedef __bf16 bf16x8 __attribute__((ext_vector_type(8)));
typedef float  f32x4  __attribute__((ext_vector_type(4)));
typedef unsigned short us8 __attribute__((ext_vector_type(8)));

__device__ __forceinline__ void async_ld16(const void* g, void* l) {
  __builtin_amdgcn_global_load_lds(
      (const __attribute__((address_space(1))) unsigned int*)g,
      (__attribute__((address_space(3))) unsigned int*)l, 16, 0, 0);
}

__device__ __forceinline__ u16 f2b(float f) {
  __hip_bfloat16 h = __float2bfloat16(f);
  return *reinterpret_cast<u16*>(&h);
}

// ---------------------------------------------------------------------------
// fp32 -> bf16 convert, 8 elements/thread (32B load, 16B store). n % 8 == 0.
// ---------------------------------------------------------------------------
__global__ void cvt_f32_bf16(const float* __restrict__ in, u16* __restrict__ out,
                             long n8) {
  const long i = (long)blockIdx.x * blockDim.x + threadIdx.x;
  if (i >= n8) return;
  const long o = i * 8;
  const float4 f0 = *(const float4*)(in + o);
  const float4 f1 = *(const float4*)(in + o + 4);
  us8 v;
  v[0] = f2b(f0.x); v[1] = f2b(f0.y); v[2] = f2b(f0.z); v[3] = f2b(f0.w);
  v[4] = f2b(f1.x); v[5] = f2b(f1.y); v[6] = f2b(f1.z); v[7] = f2b(f1.w);
  *(us8*)(out + o) = v;
}

// ---------------------------------------------------------------------------
// GEMM v3: C[M=2048, N] = A[M,K] @ B[N,K]^T + bias[N].
// 256x256 tile, BK=32, 512 threads (8 waves, 2M x 4N), per-wave 128x64 out.
// 4-slot LDS ring (128 KB), prefetch distance 3, counted vmcnt.
//
// Round-3 changes:
//  * T2-style XOR swizzle for BK=32: read slot = quad ^ ((row>>1)&3); staging
//    pre-swizzles the GLOBAL source column (linear LDS dest - rule #21, the
//    permutation is an involution). Kills the 8-way bank conflict of the
//    64B-row layout (rows 2 apart alias banks): post-swizzle each 16-lane
//    b128 group hits 8 bank-groups x 2 lanes = 2-way = free (m136).
//  * ONE barrier per iteration: vmcnt wait for tile t+1 moved BEFORE the end
//    barrier of iter t, so iter t+1's ds_reads start with no wait. Ring
//    safety: explicit lgkmcnt(0) before the barrier ensures all waves' slot
//    reads completed before anyone's stage(t+4) LDS-writes can land (those
//    are issued post-barrier, >=200cy flight).
// ---------------------------------------------------------------------------
template <int N, int K, typename OT>
__global__ __launch_bounds__(512, 2)
void gemm256(const u16* __restrict__ A, const u16* __restrict__ B,
             const float* __restrict__ bias, OT* __restrict__ C) {
  __shared__ u16 lds_[4 * 2 * 8192];  // 4 slots x (A 16KB + B 16KB) = 128 KB
  constexpr int NT = K / 32;

  const int tid  = threadIdx.x;
  const int lane = tid & 63, wave = tid >> 6;
  const int l15  = lane & 15, quad = lane >> 4;
  const int wm = wave >> 2, wn = wave & 3;  // 2M x 4N wave grid

  // XCD-aware bijective swizzle (gridDim.x % 8 == 0), B-panel grouped.
  const int nb  = (int)gridDim.x;
  const int cpx = nb >> 3;
  const int swz = ((int)blockIdx.x & 7) * cpx + ((int)blockIdx.x >> 3);
  const int by  = swz & 7;    // M-tile (M=2048 -> 8 tiles)
  const int bx  = swz >> 3;   // N-tile
  const int m0 = by * 256, n0 = bx * 256;

  f32x4 acc[8][4];
#pragma unroll
  for (int i = 0; i < 8; ++i)
#pragma unroll
    for (int j = 0; j < 4; ++j) acc[i][j] = f32x4{0.f, 0.f, 0.f, 0.f};

  // staging: thread -> LDS linear (row = tid>>2, slot = tid&3); source column
  // pre-swizzled so that LDS(row, s) holds global(row, s ^ ((row>>1)&3)).
  const int rowc = tid >> 2;
  const int wsw  = (rowc >> 1) & 3;               // staging swizzle const
  const int col8 = ((tid & 3) ^ wsw) * 8;         // swizzled 16B source slot
  const u16* gA0 = A + (size_t)(m0 + rowc) * K + col8;
  const u16* gA1 = gA0 + (size_t)128 * K;         // rows+128: same swizzle const
  const u16* gB0 = B + (size_t)(n0 + rowc) * K + col8;
  const u16* gB1 = gB0 + (size_t)128 * K;

  auto stage = [&](int t) {
    u16* s0 = lds_ + (t & 3) * 16384;
    const int k0 = t * 32;
    async_ld16(gA0 + k0, s0 + tid * 8);
    async_ld16(gA1 + k0, s0 + 4096 + tid * 8);
    async_ld16(gB0 + k0, s0 + 8192 + tid * 8);
    async_ld16(gB1 + k0, s0 + 12288 + tid * 8);
  };

  // prologue: fill 3 ring slots, guarantee tile 0 landed group-wide
  stage(0); stage(1); stage(2);
  asm volatile("s_waitcnt vmcnt(8)" ::: "memory");
  __builtin_amdgcn_s_barrier();
  __builtin_amdgcn_sched_barrier(0);

  // read-side swizzle const: row = <base> + i*16 + l15 -> (row>>1)&3 depends
  // only on l15 (i*16 and wave offsets don't touch bits 1-2).
  const int rsw = (l15 >> 1) & 3;
  const int aoff = (wm * 128 + l15) * 32 + ((quad ^ rsw) * 8);
  const int boff = 8192 + (wn * 64 + l15) * 32 + ((quad ^ rsw) * 8);

  for (int t = 0; t < NT; ++t) {
    if (t + 3 < NT) stage(t + 3);   // overwrites slot (t-1)&3: reads done (lgkm0+barrier)

    // slot t&3 fully visible (prev iter's vmcnt+barrier) -> read immediately
    const u16* sl = lds_ + (t & 3) * 16384;
    bf16x8 af[8], bfv[4];
#pragma unroll
    for (int i = 0; i < 8; ++i) af[i] = *(const bf16x8*)(sl + aoff + i * 512);
#pragma unroll
    for (int j = 0; j < 4; ++j) bfv[j] = *(const bf16x8*)(sl + boff + j * 512);

    __builtin_amdgcn_s_setprio(1);
#pragma unroll
    for (int i = 0; i < 8; ++i)
#pragma unroll
      for (int j = 0; j < 4; ++j)
        acc[i][j] = __builtin_amdgcn_mfma_f32_16x16x32_bf16(af[i], bfv[j], acc[i][j], 0, 0, 0);
    __builtin_amdgcn_s_setprio(0);

    // ring safety: my slot reads complete before I arrive at the barrier
    asm volatile("s_waitcnt lgkmcnt(0)" ::: "memory");
    // next-tile visibility: retire tile t+1's 4 loads (2 tiles stay in flight)
    const int r2 = NT - 2 - t;
    if (r2 >= 2)      asm volatile("s_waitcnt vmcnt(8)" ::: "memory");
    else if (r2 == 1) asm volatile("s_waitcnt vmcnt(4)" ::: "memory");
    else              asm volatile("s_waitcnt vmcnt(0)" ::: "memory");
    __builtin_amdgcn_s_barrier();
    __builtin_amdgcn_sched_barrier(0);
  }

  // epilogue: C/D layout col=lane&15, row=(lane>>4)*4+reg  [m89/m91]
#pragma unroll
  for (int j = 0; j < 4; ++j) {
    const int n = n0 + wn * 64 + j * 16 + l15;
    const float bv = bias[n];
#pragma unroll
    for (int i = 0; i < 8; ++i) {
      const int mr = m0 + wm * 128 + i * 16 + quad * 4;
#pragma unroll
      for (int r = 0; r < 4; ++r) {
        const float v = acc[i][j][r] + bv;
        if constexpr (sizeof(OT) == 2)
          C[(size_t)(mr + r) * N + n] = (OT)f2b(v);
        else
          C[(size_t)(mr + r) * N + n] = (OT)v;
      }
    }
  }
}

// ---------------------------------------------------------------------------
// Multi-query causal flash attention (bf16 in/out, fp32 softmax state).
// (unchanged: heavy-tiles-first grid + reg-staged K/V distance-1 prefetch)
// ---------------------------------------------------------------------------
__global__ __launch_bounds__(256, 3)
void mqa_flash(const u16* __restrict__ qkv, u16* __restrict__ attn) {
  __shared__ u16 Ks[4 * 64 * 32];  // 16 KB, kc-slab layout [kc][64][32]
  __shared__ u16 Vt[128 * 72];     // 18 KB, [d][kv] pad 64->72
  __shared__ u16 Ps[4 * 16 * 72];  // 9 KB, per-wave P[q][kv] pad 64->72
  const int tid  = threadIdx.x;
  const int lane = tid & 63, wave = tid >> 6;
  const int l15  = lane & 15, quad = lane >> 4;
  const int h  = blockIdx.x;                           // head (fast dim)
  const int qb = (int)gridDim.y - 1 - (int)blockIdx.y; // heavy tiles first
  const int q0 = qb * 64;
  const float scale = 0.088388347648318447f;  // 1/sqrt(128)

  bf16x8 qf[4];
  {
    const u16* qp = qkv + (size_t)(q0 + wave * 16 + l15) * NKV + h * HD_ + quad * 8;
#pragma unroll
    for (int kc = 0; kc < 4; ++kc) qf[kc] = *(const bf16x8*)(qp + kc * 32);
  }

  f32x4 oacc[8];
#pragma unroll
  for (int nd = 0; nd < 8; ++nd) oacc[nd] = f32x4{0.f, 0.f, 0.f, 0.f};
  float mrun[4], lrun[4];
#pragma unroll
  for (int r = 0; r < 4; ++r) { mrun[r] = -1e30f; lrun[r] = 0.f; }

  const int krow = tid >> 2, kc8 = (tid & 3) * 8;
  const int kv2 = lane & 31;
  const int dg  = wave * 2 + (lane >> 5);

  auto load_tile = [&](int t, us8* kr, us8* vr) {
    const int kv0 = t * 64;
    const u16* kp = qkv + (size_t)(kv0 + krow) * NKV + HID_ + kc8;
#pragma unroll
    for (int r = 0; r < 4; ++r) kr[r] = *(const us8*)(kp + r * 32);
    const u16* vp = qkv + (size_t)(kv0 + kv2 * 2) * NKV + HID_ + HD_ + dg * 16;
    vr[0] = *(const us8*)(vp);
    vr[1] = *(const us8*)(vp + 8);
    vr[2] = *(const us8*)(vp + NKV);
    vr[3] = *(const us8*)(vp + NKV + 8);
  };

  auto stage_tile = [&](const us8* kr, const us8* vr) {
    u16* kd = Ks + tid * 8;
#pragma unroll
    for (int r = 0; r < 4; ++r) *(us8*)(kd + r * 2048) = kr[r];
#pragma unroll
    for (int i = 0; i < 8; ++i) {
      unsigned v0 = (unsigned)vr[0][i] | ((unsigned)vr[2][i] << 16);
      unsigned v1 = (unsigned)vr[1][i] | ((unsigned)vr[3][i] << 16);
      *(unsigned*)(Vt + (dg * 16 + i) * 72 + kv2 * 2) = v0;
      *(unsigned*)(Vt + (dg * 16 + 8 + i) * 72 + kv2 * 2) = v1;
    }
  };

  auto compute_tile = [&](int t) {
    const int kv0 = t * 64;
    f32x4 s[4];
#pragma unroll
    for (int nt = 0; nt < 4; ++nt) {
      f32x4 c4 = f32x4{0.f, 0.f, 0.f, 0.f};
#pragma unroll
      for (int kc = 0; kc < 4; ++kc) {
        bf16x8 kf = *(const bf16x8*)(Ks + kc * 2048 + (nt * 16 + l15) * 32 + quad * 8);
        c4 = __builtin_amdgcn_mfma_f32_16x16x32_bf16(qf[kc], kf, c4, 0, 0, 0);
      }
      s[nt] = c4;
    }

    float mt[4] = {-1e30f, -1e30f, -1e30f, -1e30f};
    if (t == qb) {
#pragma unroll
      for (int nt = 0; nt < 4; ++nt) {
        const int kvg = kv0 + nt * 16 + l15;
#pragma unroll
        for (int r = 0; r < 4; ++r) {
          const int qg = q0 + wave * 16 + quad * 4 + r;
          float v = s[nt][r] * scale;
          v = (kvg <= qg) ? v : -1e30f;
          s[nt][r] = v;
          mt[r] = fmaxf(mt[r], v);
        }
      }
    } else {
#pragma unroll
      for (int nt = 0; nt < 4; ++nt)
#pragma unroll
        for (int r = 0; r < 4; ++r) {
          const float v = s[nt][r] * scale;
          s[nt][r] = v;
          mt[r] = fmaxf(mt[r], v);
        }
    }
#pragma unroll
    for (int off = 1; off < 16; off <<= 1)
#pragma unroll
      for (int r = 0; r < 4; ++r) mt[r] = fmaxf(mt[r], __shfl_xor(mt[r], off));

    float alpha[4], rsum[4];
#pragma unroll
    for (int r = 0; r < 4; ++r) {
      const float mnew = fmaxf(mrun[r], mt[r]);
      alpha[r] = __expf(mrun[r] - mnew);
      mrun[r] = mnew;
      rsum[r] = 0.f;
    }
    u16* pw = Ps + wave * (16 * 72);
#pragma unroll
    for (int nt = 0; nt < 4; ++nt)
#pragma unroll
      for (int r = 0; r < 4; ++r) {
        const float p = __expf(s[nt][r] - mrun[r]);
        rsum[r] += p;
        pw[(quad * 4 + r) * 72 + nt * 16 + l15] = f2b(p);
      }
#pragma unroll
    for (int off = 1; off < 16; off <<= 1)
#pragma unroll
      for (int r = 0; r < 4; ++r) rsum[r] += __shfl_xor(rsum[r], off);
#pragma unroll
    for (int r = 0; r < 4; ++r) lrun[r] = lrun[r] * alpha[r] + rsum[r];
#pragma unroll
    for (int nd = 0; nd < 8; ++nd)
#pragma unroll
      for (int r = 0; r < 4; ++r) oacc[nd][r] *= alpha[r];

#pragma unroll
    for (int kc2 = 0; kc2 < 2; ++kc2) {
      bf16x8 pf = *(const bf16x8*)(pw + l15 * 72 + kc2 * 32 + quad * 8);
#pragma unroll
      for (int nd = 0; nd < 8; ++nd) {
        bf16x8 vf = *(const bf16x8*)(Vt + (nd * 16 + l15) * 72 + kc2 * 32 + quad * 8);
        oacc[nd] = __builtin_amdgcn_mfma_f32_16x16x32_bf16(pf, vf, oacc[nd], 0, 0, 0);
      }
    }
  };

  us8 kA[4], vA[4], kB[4], vB[4];
  load_tile(0, kA, vA);
  for (int t = 0; t <= qb; ++t) {
    const int tn = (t < qb) ? t + 1 : t;
    if (!(t & 1)) {
      stage_tile(kA, vA);
      load_tile(tn, kB, vB);
    } else {
      stage_tile(kB, vB);
      load_tile(tn, kA, vA);
    }
    __syncthreads();
    compute_tile(t);
    __syncthreads();
  }

#pragma unroll
  for (int r = 0; r < 4; ++r) {
    const int qg = q0 + wave * 16 + quad * 4 + r;
    const float inv = 1.f / lrun[r];
#pragma unroll
    for (int nd = 0; nd < 8; ++nd)
      attn[(size_t)qg * HID_ + h * HD_ + nd * 16 + l15] = f2b(oacc[nd][r] * inv);
  }
}

// ---------------------------------------------------------------------------
extern "C" void kernel_launch(void* const* d_in, const int* in_sizes, int n_in,
                              void* d_out, int out_size, void* d_ws, size_t ws_size,
                              hipStream_t stream) {
  const float* x    = (const float*)d_in[0];  // [2048, 6144] fp32
  const float* wqkv = (const float*)d_in[1];  // [6400, 6144] fp32
  const float* bqkv = (const float*)d_in[2];  // [6400] fp32
  const float* wo   = (const float*)d_in[3];  // [6144, 6144] fp32
  const float* bo   = (const float*)d_in[4];  // [6144] fp32
  float* out = (float*)d_out;                 // [2048, 6144] fp32

  // workspace layout (all 16B-aligned)
  u16* xb     = (u16*)d_ws;                             // 25.2 MB
  u16* wqkvb  = xb + (size_t)SEQ * HID_;                // 78.6 MB
  u16* wob    = wqkvb + (size_t)NKV * HID_;             // 75.5 MB
  u16* qkvws  = wob + (size_t)HID_ * HID_;              // 26.2 MB
  u16* attnws = qkvws + (size_t)SEQ * NKV;              // 25.2 MB
  // total ~230.7 MB

  // 0) fp32 -> bf16 converts
  {
    const long n8x = (long)SEQ * HID_ / 8;
    cvt_f32_bf16<<<(n8x + 255) / 256, 256, 0, stream>>>(x, xb, n8x);
    const long n8q = (long)NKV * HID_ / 8;
    cvt_f32_bf16<<<(n8q + 255) / 256, 256, 0, stream>>>(wqkv, wqkvb, n8q);
    const long n8o = (long)HID_ * HID_ / 8;
    cvt_f32_bf16<<<(n8o + 255) / 256, 256, 0, stream>>>(wo, wob, n8o);
  }

  // 1) fused QKV projection (bf16 out): grid 25*8 = 200 blocks (%8==0)
  gemm256<NKV, HID_, u16><<<dim3(200), 512, 0, stream>>>(xb, wqkvb, bqkv, qkvws);
  // 2) multi-query causal flash attention (h fast, heavy q-tiles first)
  mqa_flash<<<dim3(NH_, SEQ / 64), 256, 0, stream>>>(qkvws, attnws);
  // 3) output projection (fp32 out): grid 24*8 = 192 blocks (%8==0)
  gemm256<HID_, HID_, float><<<dim3(192), 512, 0, stream>>>(attnws, wob, bo, out);
}

// Round 4
// 856.031 us; speedup vs baseline: 1.2076x; 1.0204x over previous
//
#include <hip/hip_runtime.h>
#include <hip/hip_bf16.h>
#include <cstdint>
#include <cstddef>

// Problem constants (B=1)
#define SEQ  2048
#define HID_ 6144
#define NKV  6400   // QKV_OUT
#define NH_  48
#define HD_  128

typedef unsigned short u16;
typedef __bf16 bf16x8 __attribute__((ext_vector_type(8)));
typedef float  f32x4  __attribute__((ext_vector_type(4)));
typedef unsigned short us8 __attribute__((ext_vector_type(8)));

__device__ __forceinline__ void async_ld16(const void* g, void* l) {
  __builtin_amdgcn_global_load_lds(
      (const __attribute__((address_space(1))) unsigned int*)g,
      (__attribute__((address_space(3))) unsigned int*)l, 16, 0, 0);
}

__device__ __forceinline__ u16 f2b(float f) {
  __hip_bfloat16 h = __float2bfloat16(f);
  return *reinterpret_cast<u16*>(&h);
}

// ---------------------------------------------------------------------------
// fp32 -> bf16 convert, 8 elements/thread (32B load, 16B store). n % 8 == 0.
// ---------------------------------------------------------------------------
__global__ void cvt_f32_bf16(const float* __restrict__ in, u16* __restrict__ out,
                             long n8) {
  const long i = (long)blockIdx.x * blockDim.x + threadIdx.x;
  if (i >= n8) return;
  const long o = i * 8;
  const float4 f0 = *(const float4*)(in + o);
  const float4 f1 = *(const float4*)(in + o + 4);
  us8 v;
  v[0] = f2b(f0.x); v[1] = f2b(f0.y); v[2] = f2b(f0.z); v[3] = f2b(f0.w);
  v[4] = f2b(f1.x); v[5] = f2b(f1.y); v[6] = f2b(f1.z); v[7] = f2b(f1.w);
  *(us8*)(out + o) = v;
}

// ---------------------------------------------------------------------------
// GEMM v4: C[M=2048, N] = A[M,K] @ B[N,K]^T + bias[N].
// 256x256 tile, BK=32, 512 threads (8 waves, 2M x 4N), per-wave 128x64 out.
// 4-slot LDS ring (128 KB), prefetch distance 3, counted vmcnt, XOR swizzle
// (round-3, conflicts measured 0).
//
// Round-4 change: REGISTER-PIPELINED FRAGMENTS across the barrier.
// During iter t: read tile t+1's fragments into the OTHER frag buffer while
// MFMAing tile t from registers loaded last iter. The 12 ds_read_b128 and
// 32 MFMA in each barrier window are now independent -> both pipes busy
// (previously serial: reads(t) -> MFMA(t) added ~250cy latency per iter).
// Parity-unrolled (2 tiles/body, named bufs - rule #20).
// Ledger:
//  * reads(t+1) stay post-barrier (LDS visibility);
//  * end-of-iter-t wait retires stage(t+2) (vmcnt(4)); issued at iter t-1,
//    ~2 iters of flight >= HBM latency;
//  * stage(t+3) (issued iter t, post-barrier) overwrites slot (t-1)&3 whose
//    frag reads (issued iter t-2) were lgkm0-drained two barriers earlier;
//  * final body reads "tile NT" (slot 0, stale data, no writer in flight)
//    into a buffer that is never consumed - harmless, keeps loop straight.
// ---------------------------------------------------------------------------
template <int N, int K, typename OT>
__global__ __launch_bounds__(512, 2)
void gemm256(const u16* __restrict__ A, const u16* __restrict__ B,
             const float* __restrict__ bias, OT* __restrict__ C) {
  __shared__ u16 lds_[4 * 16384];  // 4 slots x (A 16KB + B 16KB) = 128 KB
  constexpr int NT = K / 32;       // 192, even

  const int tid  = threadIdx.x;
  const int lane = tid & 63, wave = tid >> 6;
  const int l15  = lane & 15, quad = lane >> 4;
  const int wm = wave >> 2, wn = wave & 3;  // 2M x 4N wave grid

  // XCD-aware bijective swizzle (gridDim.x % 8 == 0), B-panel grouped.
  const int nb  = (int)gridDim.x;
  const int cpx = nb >> 3;
  const int swz = ((int)blockIdx.x & 7) * cpx + ((int)blockIdx.x >> 3);
  const int by  = swz & 7;    // M-tile (M=2048 -> 8 tiles)
  const int bx  = swz >> 3;   // N-tile
  const int m0 = by * 256, n0 = bx * 256;

  f32x4 acc[8][4];
#pragma unroll
  for (int i = 0; i < 8; ++i)
#pragma unroll
    for (int j = 0; j < 4; ++j) acc[i][j] = f32x4{0.f, 0.f, 0.f, 0.f};

  // staging: thread -> LDS linear (row = tid>>2, slot16 = tid&3); source
  // column pre-swizzled: LDS(row, s) holds global(row, s ^ ((row>>1)&3)).
  const int rowc = tid >> 2;
  const int wsw  = (rowc >> 1) & 3;
  const int col8 = ((tid & 3) ^ wsw) * 8;
  const u16* gA0 = A + (size_t)(m0 + rowc) * K + col8;
  const u16* gA1 = gA0 + (size_t)128 * K;
  const u16* gB0 = B + (size_t)(n0 + rowc) * K + col8;
  const u16* gB1 = gB0 + (size_t)128 * K;

  auto stage = [&](int t) {
    u16* s0 = lds_ + (t & 3) * 16384;
    const int k0 = t * 32;
    async_ld16(gA0 + k0, s0 + tid * 8);
    async_ld16(gA1 + k0, s0 + 4096 + tid * 8);
    async_ld16(gB0 + k0, s0 + 8192 + tid * 8);
    async_ld16(gB1 + k0, s0 + 12288 + tid * 8);
  };

  // read-side swizzle const (row bits 1-2 come only from l15)
  const int rsw = (l15 >> 1) & 3;
  const int aoff = (wm * 128 + l15) * 32 + ((quad ^ rsw) * 8);
  const int boff = 8192 + (wn * 64 + l15) * 32 + ((quad ^ rsw) * 8);

  auto readFrags = [&](int t, bf16x8* af, bf16x8* bfv) {
    const u16* sl = lds_ + (t & 3) * 16384;
#pragma unroll
    for (int i = 0; i < 8; ++i) af[i] = *(const bf16x8*)(sl + aoff + i * 512);
#pragma unroll
    for (int j = 0; j < 4; ++j) bfv[j] = *(const bf16x8*)(sl + boff + j * 512);
  };

  auto mfmas = [&](const bf16x8* af, const bf16x8* bfv) {
    __builtin_amdgcn_s_setprio(1);
#pragma unroll
    for (int i = 0; i < 8; ++i)
#pragma unroll
      for (int j = 0; j < 4; ++j)
        acc[i][j] = __builtin_amdgcn_mfma_f32_16x16x32_bf16(af[i], bfv[j], acc[i][j], 0, 0, 0);
    __builtin_amdgcn_s_setprio(0);
  };

  // prologue: 3 tiles staged; retire tiles 0,1 (leave tile 2 in flight)
  stage(0); stage(1); stage(2);
  asm volatile("s_waitcnt vmcnt(4)" ::: "memory");
  __builtin_amdgcn_s_barrier();
  __builtin_amdgcn_sched_barrier(0);

  bf16x8 afA[8], bfA[4], afB[8], bfB[4];
  readFrags(0, afA, bfA);

  for (int tt = 0; tt < NT / 2; ++tt) {
    const int t = tt * 2;
    // ---- even tile t: compute bufA, read t+1 into bufB ----
    if (t + 3 < NT) stage(t + 3);
    readFrags(t + 1, afB, bfB);     // independent of mfmas(bufA)
    mfmas(afA, bfA);
    asm volatile("s_waitcnt lgkmcnt(0)" ::: "memory");  // frag reads done
    if (t + 3 < NT) asm volatile("s_waitcnt vmcnt(4)" ::: "memory");
    else            asm volatile("s_waitcnt vmcnt(0)" ::: "memory");
    __builtin_amdgcn_s_barrier();
    __builtin_amdgcn_sched_barrier(0);

    // ---- odd tile t+1: compute bufB, read t+2 into bufA ----
    if (t + 4 < NT) stage(t + 4);
    readFrags(t + 2, afA, bfA);     // t+2==NT on last body: stale slot, unused
    mfmas(afB, bfB);
    asm volatile("s_waitcnt lgkmcnt(0)" ::: "memory");
    if (t + 4 < NT) asm volatile("s_waitcnt vmcnt(4)" ::: "memory");
    else            asm volatile("s_waitcnt vmcnt(0)" ::: "memory");
    __builtin_amdgcn_s_barrier();
    __builtin_amdgcn_sched_barrier(0);
  }

  // epilogue: C/D layout col=lane&15, row=(lane>>4)*4+reg  [m89/m91]
#pragma unroll
  for (int j = 0; j < 4; ++j) {
    const int n = n0 + wn * 64 + j * 16 + l15;
    const float bv = bias[n];
#pragma unroll
    for (int i = 0; i < 8; ++i) {
      const int mr = m0 + wm * 128 + i * 16 + quad * 4;
#pragma unroll
      for (int r = 0; r < 4; ++r) {
        const float v = acc[i][j][r] + bv;
        if constexpr (sizeof(OT) == 2)
          C[(size_t)(mr + r) * N + n] = (OT)f2b(v);
        else
          C[(size_t)(mr + r) * N + n] = (OT)v;
      }
    }
  }
}

// ---------------------------------------------------------------------------
// Multi-query causal flash attention (bf16 in/out, fp32 softmax state).
// (unchanged: heavy-tiles-first grid + reg-staged K/V distance-1 prefetch)
// ---------------------------------------------------------------------------
__global__ __launch_bounds__(256, 3)
void mqa_flash(const u16* __restrict__ qkv, u16* __restrict__ attn) {
  __shared__ u16 Ks[4 * 64 * 32];  // 16 KB, kc-slab layout [kc][64][32]
  __shared__ u16 Vt[128 * 72];     // 18 KB, [d][kv] pad 64->72
  __shared__ u16 Ps[4 * 16 * 72];  // 9 KB, per-wave P[q][kv] pad 64->72
  const int tid  = threadIdx.x;
  const int lane = tid & 63, wave = tid >> 6;
  const int l15  = lane & 15, quad = lane >> 4;
  const int h  = blockIdx.x;                           // head (fast dim)
  const int qb = (int)gridDim.y - 1 - (int)blockIdx.y; // heavy tiles first
  const int q0 = qb * 64;
  const float scale = 0.088388347648318447f;  // 1/sqrt(128)

  bf16x8 qf[4];
  {
    const u16* qp = qkv + (size_t)(q0 + wave * 16 + l15) * NKV + h * HD_ + quad * 8;
#pragma unroll
    for (int kc = 0; kc < 4; ++kc) qf[kc] = *(const bf16x8*)(qp + kc * 32);
  }

  f32x4 oacc[8];
#pragma unroll
  for (int nd = 0; nd < 8; ++nd) oacc[nd] = f32x4{0.f, 0.f, 0.f, 0.f};
  float mrun[4], lrun[4];
#pragma unroll
  for (int r = 0; r < 4; ++r) { mrun[r] = -1e30f; lrun[r] = 0.f; }

  const int krow = tid >> 2, kc8 = (tid & 3) * 8;
  const int kv2 = lane & 31;
  const int dg  = wave * 2 + (lane >> 5);

  auto load_tile = [&](int t, us8* kr, us8* vr) {
    const int kv0 = t * 64;
    const u16* kp = qkv + (size_t)(kv0 + krow) * NKV + HID_ + kc8;
#pragma unroll
    for (int r = 0; r < 4; ++r) kr[r] = *(const us8*)(kp + r * 32);
    const u16* vp = qkv + (size_t)(kv0 + kv2 * 2) * NKV + HID_ + HD_ + dg * 16;
    vr[0] = *(const us8*)(vp);
    vr[1] = *(const us8*)(vp + 8);
    vr[2] = *(const us8*)(vp + NKV);
    vr[3] = *(const us8*)(vp + NKV + 8);
  };

  auto stage_tile = [&](const us8* kr, const us8* vr) {
    u16* kd = Ks + tid * 8;
#pragma unroll
    for (int r = 0; r < 4; ++r) *(us8*)(kd + r * 2048) = kr[r];
#pragma unroll
    for (int i = 0; i < 8; ++i) {
      unsigned v0 = (unsigned)vr[0][i] | ((unsigned)vr[2][i] << 16);
      unsigned v1 = (unsigned)vr[1][i] | ((unsigned)vr[3][i] << 16);
      *(unsigned*)(Vt + (dg * 16 + i) * 72 + kv2 * 2) = v0;
      *(unsigned*)(Vt + (dg * 16 + 8 + i) * 72 + kv2 * 2) = v1;
    }
  };

  auto compute_tile = [&](int t) {
    const int kv0 = t * 64;
    f32x4 s[4];
#pragma unroll
    for (int nt = 0; nt < 4; ++nt) {
      f32x4 c4 = f32x4{0.f, 0.f, 0.f, 0.f};
#pragma unroll
      for (int kc = 0; kc < 4; ++kc) {
        bf16x8 kf = *(const bf16x8*)(Ks + kc * 2048 + (nt * 16 + l15) * 32 + quad * 8);
        c4 = __builtin_amdgcn_mfma_f32_16x16x32_bf16(qf[kc], kf, c4, 0, 0, 0);
      }
      s[nt] = c4;
    }

    float mt[4] = {-1e30f, -1e30f, -1e30f, -1e30f};
    if (t == qb) {
#pragma unroll
      for (int nt = 0; nt < 4; ++nt) {
        const int kvg = kv0 + nt * 16 + l15;
#pragma unroll
        for (int r = 0; r < 4; ++r) {
          const int qg = q0 + wave * 16 + quad * 4 + r;
          float v = s[nt][r] * scale;
          v = (kvg <= qg) ? v : -1e30f;
          s[nt][r] = v;
          mt[r] = fmaxf(mt[r], v);
        }
      }
    } else {
#pragma unroll
      for (int nt = 0; nt < 4; ++nt)
#pragma unroll
        for (int r = 0; r < 4; ++r) {
          const float v = s[nt][r] * scale;
          s[nt][r] = v;
          mt[r] = fmaxf(mt[r], v);
        }
    }
#pragma unroll
    for (int off = 1; off < 16; off <<= 1)
#pragma unroll
      for (int r = 0; r < 4; ++r) mt[r] = fmaxf(mt[r], __shfl_xor(mt[r], off));

    float alpha[4], rsum[4];
#pragma unroll
    for (int r = 0; r < 4; ++r) {
      const float mnew = fmaxf(mrun[r], mt[r]);
      alpha[r] = __expf(mrun[r] - mnew);
      mrun[r] = mnew;
      rsum[r] = 0.f;
    }
    u16* pw = Ps + wave * (16 * 72);
#pragma unroll
    for (int nt = 0; nt < 4; ++nt)
#pragma unroll
      for (int r = 0; r < 4; ++r) {
        const float p = __expf(s[nt][r] - mrun[r]);
        rsum[r] += p;
        pw[(quad * 4 + r) * 72 + nt * 16 + l15] = f2b(p);
      }
#pragma unroll
    for (int off = 1; off < 16; off <<= 1)
#pragma unroll
      for (int r = 0; r < 4; ++r) rsum[r] += __shfl_xor(rsum[r], off);
#pragma unroll
    for (int r = 0; r < 4; ++r) lrun[r] = lrun[r] * alpha[r] + rsum[r];
#pragma unroll
    for (int nd = 0; nd < 8; ++nd)
#pragma unroll
      for (int r = 0; r < 4; ++r) oacc[nd][r] *= alpha[r];

#pragma unroll
    for (int kc2 = 0; kc2 < 2; ++kc2) {
      bf16x8 pf = *(const bf16x8*)(pw + l15 * 72 + kc2 * 32 + quad * 8);
#pragma unroll
      for (int nd = 0; nd < 8; ++nd) {
        bf16x8 vf = *(const bf16x8*)(Vt + (nd * 16 + l15) * 72 + kc2 * 32 + quad * 8);
        oacc[nd] = __builtin_amdgcn_mfma_f32_16x16x32_bf16(pf, vf, oacc[nd], 0, 0, 0);
      }
    }
  };

  us8 kA[4], vA[4], kB[4], vB[4];
  load_tile(0, kA, vA);
  for (int t = 0; t <= qb; ++t) {
    const int tn = (t < qb) ? t + 1 : t;
    if (!(t & 1)) {
      stage_tile(kA, vA);
      load_tile(tn, kB, vB);
    } else {
      stage_tile(kB, vB);
      load_tile(tn, kA, vA);
    }
    __syncthreads();
    compute_tile(t);
    __syncthreads();
  }

#pragma unroll
  for (int r = 0; r < 4; ++r) {
    const int qg = q0 + wave * 16 + quad * 4 + r;
    const float inv = 1.f / lrun[r];
#pragma unroll
    for (int nd = 0; nd < 8; ++nd)
      attn[(size_t)qg * HID_ + h * HD_ + nd * 16 + l15] = f2b(oacc[nd][r] * inv);
  }
}

// ---------------------------------------------------------------------------
extern "C" void kernel_launch(void* const* d_in, const int* in_sizes, int n_in,
                              void* d_out, int out_size, void* d_ws, size_t ws_size,
                              hipStream_t stream) {
  const float* x    = (const float*)d_in[0];  // [2048, 6144] fp32
  const float* wqkv = (const float*)d_in[1];  // [6400, 6144] fp32
  const float* bqkv = (const float*)d_in[2];  // [6400] fp32
  const float* wo   = (const float*)d_in[3];  // [6144, 6144] fp32
  const float* bo   = (const float*)d_in[4];  // [6144] fp32
  float* out = (float*)d_out;                 // [2048, 6144] fp32

  // workspace layout (all 16B-aligned)
  u16* xb     = (u16*)d_ws;                             // 25.2 MB
  u16* wqkvb  = xb + (size_t)SEQ * HID_;                // 78.6 MB
  u16* wob    = wqkvb + (size_t)NKV * HID_;             // 75.5 MB
  u16* qkvws  = wob + (size_t)HID_ * HID_;              // 26.2 MB
  u16* attnws = qkvws + (size_t)SEQ * NKV;              // 25.2 MB
  // total ~230.7 MB

  // 0) fp32 -> bf16 converts
  {
    const long n8x = (long)SEQ * HID_ / 8;
    cvt_f32_bf16<<<(n8x + 255) / 256, 256, 0, stream>>>(x, xb, n8x);
    const long n8q = (long)NKV * HID_ / 8;
    cvt_f32_bf16<<<(n8q + 255) / 256, 256, 0, stream>>>(wqkv, wqkvb, n8q);
    const long n8o = (long)HID_ * HID_ / 8;
    cvt_f32_bf16<<<(n8o + 255) / 256, 256, 0, stream>>>(wo, wob, n8o);
  }

  // 1) fused QKV projection (bf16 out): grid 25*8 = 200 blocks (%8==0)
  gemm256<NKV, HID_, u16><<<dim3(200), 512, 0, stream>>>(xb, wqkvb, bqkv, qkvws);
  // 2) multi-query causal flash attention (h fast, heavy q-tiles first)
  mqa_flash<<<dim3(NH_, SEQ / 64), 256, 0, stream>>>(qkvws, attnws);
  // 3) output projection (fp32 out): grid 24*8 = 192 blocks (%8==0)
  gemm256<HID_, HID_, float><<<dim3(192), 512, 0, stream>>>(attnws, wob, bo, out);
}